// Round 12
// baseline (30.587 us; speedup 1.0000x reference)
//
#include <hip/hip_runtime.h>

#define N 256
#define LANES 64
#define NPAIRS 136   // pairs 0..127 real, 128..135 pad {0,0,0,+INF}

// lane t gets src[t-1]; lane 0 gets old (runtime VGPR). Proven semantics (R9).
__device__ __forceinline__ float dpp_shr1(float old_v, float v) {
    return __int_as_float(__builtin_amdgcn_update_dpp(
        __float_as_int(old_v), __float_as_int(v), 0x138 /*wave_shr:1*/, 0xf, 0xf, false));
}
// lane t gets src[t-1]; lane 0 gets +INF.
__device__ __forceinline__ float dpp_shr1_inf(float v) {
    return __int_as_float(__builtin_amdgcn_update_dpp(
        0x7f800000, __float_as_int(v), 0x138, 0xf, 0xf, false));
}
// lane t gets src[t+1]; lane 63 gets 0 under EITHER bound_ctrl polarity
// (old=0 AND bound_ctrl=true). Shifted-in zeros are never consumed (see phases).
__device__ __forceinline__ float dpp_shl1_z(float v) {
    return __int_as_float(__builtin_amdgcn_update_dpp(
        0, __float_as_int(v), 0x130 /*wave_shl:1*/, 0xf, 0xf, true));
}

// One wave per batch; lane t owns rows 4t..4t+3; 2 columns (1 pair) per step.
// The 64-pair sliding window of y lives IN REGISTERS across lanes:
//   Y (8 regs) = pair(s-t), shifts DOWN one lane per step (wave_shr),
//   F (8 regs) = pair(s+1+t) future-FIFO, shifts UP (wave_shl), refilled from
//   LDS once per 64 steps. Main loop has ZERO LDS ops -> no lgkmcnt stalls.
__global__ __launch_bounds__(64) void frechet_rot(
    const float* __restrict__ x,   // [B, 256, 3]
    const float* __restrict__ y,   // [B, 256, 3]
    float* __restrict__ out)       // [B]
{
    const int b = blockIdx.x;
    const int t = threadIdx.x;     // 0..63

    const float INF = __builtin_inff();

    __shared__ float4 ldsY[2 * NPAIRS];   // pair p -> ldsY[2p], ldsY[2p+1]

    // pads: pairs 128..135
    if (t < 8) {
        const float4 padv = make_float4(0.0f, 0.0f, 0.0f, INF);
        ldsY[2 * (128 + t)]     = padv;
        ldsY[2 * (128 + t) + 1] = padv;
    }
    // real y: cols t, t+64, t+128, t+192 -> {y0,y1,y2,|y|^2}
    #pragma unroll
    for (int k = 0; k < 4; ++k) {
        const int c = t + 64 * k;
        const float y0 = y[(b * N + c) * 3 + 0];
        const float y1 = y[(b * N + c) * 3 + 1];
        const float y2 = y[(b * N + c) * 3 + 2];
        ldsY[2 * (c >> 1) + (c & 1)] = make_float4(y0, y1, y2, y0*y0 + y1*y1 + y2*y2);
    }

    // x rows 4t..4t+3, pre-scaled: cost = |x|^2 + |y|^2 - 2 x.y
    float xm0[4], xm1[4], xm2[4], sx[4];
    #pragma unroll
    for (int r = 0; r < 4; ++r) {
        const float a0 = x[(b * N + 4 * t + r) * 3 + 0];
        const float a1 = x[(b * N + 4 * t + r) * 3 + 1];
        const float a2 = x[(b * N + 4 * t + r) * 3 + 2];
        xm0[r] = -2.0f * a0;
        xm1[r] = -2.0f * a1;
        xm2[r] = -2.0f * a2;
        sx[r] = a0 * a0 + a1 * a1 + a2 * a2;
    }
    __syncthreads();

    // Y init: lane 0 = pair 0, others = pad
    float y0a, y1a, y2a, ysa, y0b, y1b, y2b, ysb;
    {
        const float4 pa = ldsY[0], pb = ldsY[1];
        const bool L0 = (t == 0);
        y0a = L0 ? pa.x : 0.0f;  y1a = L0 ? pa.y : 0.0f;
        y2a = L0 ? pa.z : 0.0f;  ysa = L0 ? pa.w : INF;
        y0b = L0 ? pb.x : 0.0f;  y1b = L0 ? pb.y : 0.0f;
        y2b = L0 ? pb.z : 0.0f;  ysb = L0 ? pb.w : INF;
    }
    // F init: lane t = pair(1+t)  (pairs 1..64, all real)
    float f0a, f1a, f2a, fsa, f0b, f1b, f2b, fsb;
    {
        const float4 fa = ldsY[2 * (1 + t)], fb = ldsY[2 * (1 + t) + 1];
        f0a = fa.x; f1a = fa.y; f2a = fa.z; fsa = fa.w;
        f0b = fb.x; f1b = fb.y; f2b = fb.z; fsb = fb.w;
    }

    float lv0 = INF, lv1 = INF, lv2 = INF, lv3 = INF;
    float cb0 = INF, cb1 = INF;
    float diagv = (t == 0) ? 0.0f : INF;   // seeds D[0][0]

    #define STEP                                                                    \
    {                                                                               \
        const float u0 = dpp_shr1_inf(cb0);                                         \
        const float u1 = dpp_shr1_inf(cb1);                                         \
        const float ca0 = fmaf(xm0[0], y0a, fmaf(xm1[0], y1a, fmaf(xm2[0], y2a, sx[0] + ysa))); \
        const float ca1 = fmaf(xm0[1], y0a, fmaf(xm1[1], y1a, fmaf(xm2[1], y2a, sx[1] + ysa))); \
        const float ca2 = fmaf(xm0[2], y0a, fmaf(xm1[2], y1a, fmaf(xm2[2], y2a, sx[2] + ysa))); \
        const float ca3 = fmaf(xm0[3], y0a, fmaf(xm1[3], y1a, fmaf(xm2[3], y2a, sx[3] + ysa))); \
        const float cc0 = fmaf(xm0[0], y0b, fmaf(xm1[0], y1b, fmaf(xm2[0], y2b, sx[0] + ysb))); \
        const float cc1 = fmaf(xm0[1], y0b, fmaf(xm1[1], y1b, fmaf(xm2[1], y2b, sx[1] + ysb))); \
        const float cc2 = fmaf(xm0[2], y0b, fmaf(xm1[2], y1b, fmaf(xm2[2], y2b, sx[2] + ysb))); \
        const float cc3 = fmaf(xm0[3], y0b, fmaf(xm1[3], y1b, fmaf(xm2[3], y2b, sx[3] + ysb))); \
        const float v0 = fmaxf(ca0, fminf(fminf(u0, lv0), diagv));                  \
        const float v1 = fmaxf(ca1, fminf(fminf(v0, lv1), lv0));                    \
        const float v2 = fmaxf(ca2, fminf(fminf(v1, lv2), lv1));                    \
        const float v3 = fmaxf(ca3, fminf(fminf(v2, lv3), lv2));                    \
        const float w0 = fmaxf(cc0, fminf(fminf(u1, v0), u0));                      \
        const float w1 = fmaxf(cc1, fminf(fminf(w0, v1), v0));                      \
        const float w2 = fmaxf(cc2, fminf(fminf(w1, v2), v1));                      \
        const float w3 = fmaxf(cc3, fminf(fminf(w2, v3), v2));                      \
        lv0 = w0; lv1 = w1; lv2 = w2; lv3 = w3;                                     \
        cb0 = v3; cb1 = w3;                                                         \
        diagv = u1;                                                                 \
        /* rotate Y down one lane, inject F[0] at lane 0 */                         \
        y0a = dpp_shr1(f0a, y0a); y1a = dpp_shr1(f1a, y1a);                         \
        y2a = dpp_shr1(f2a, y2a); ysa = dpp_shr1(fsa, ysa);                         \
        y0b = dpp_shr1(f0b, y0b); y1b = dpp_shr1(f1b, y1b);                         \
        y2b = dpp_shr1(f2b, y2b); ysb = dpp_shr1(fsb, ysb);                         \
        /* rotate F up one lane (shift-in zeros are never consumed) */              \
        f0a = dpp_shl1_z(f0a); f1a = dpp_shl1_z(f1a);                               \
        f2a = dpp_shl1_z(f2a); fsa = dpp_shl1_z(fsa);                               \
        f0b = dpp_shl1_z(f0b); f1b = dpp_shl1_z(f1b);                               \
        f2b = dpp_shl1_z(f2b); fsb = dpp_shl1_z(fsb);                               \
    }

    // phase 1: steps 0..63 (F init holds pairs 1..64)
    #pragma unroll 4
    for (int s = 0; s < 64; ++s) STEP;

    // refill F: lane t = pair(65+t)  (65..127 real, 128 = LDS pad)
    {
        const float4 fa = ldsY[2 * (65 + t)], fb = ldsY[2 * (65 + t) + 1];
        f0a = fa.x; f1a = fa.y; f2a = fa.z; fsa = fa.w;
        f0b = fb.x; f1b = fb.y; f2b = fb.z; fsb = fb.w;
    }

    // phase 2: steps 64..127
    #pragma unroll 4
    for (int s = 0; s < 64; ++s) STEP;

    // beyond pair 128: everything is pad
    f0a = 0.0f; f1a = 0.0f; f2a = 0.0f; fsa = INF;
    f0b = 0.0f; f1b = 0.0f; f2b = 0.0f; fsb = INF;

    // phase 3: steps 128..190 (63 steps; lane 63 finishes pair 127 at s=190)
    #pragma unroll 3
    for (int s = 0; s < 63; ++s) STEP;

    #undef STEP

    if (t == LANES - 1)
        out[b] = cb1;   // D[255][255]
}

extern "C" void kernel_launch(void* const* d_in, const int* in_sizes, int n_in,
                              void* d_out, int out_size, void* d_ws, size_t ws_size,
                              hipStream_t stream) {
    const float* x = (const float*)d_in[0];
    const float* y = (const float*)d_in[1];
    float* out = (float*)d_out;

    const int B = in_sizes[0] / (N * 3);   // 128
    frechet_rot<<<B, LANES, 0, stream>>>(x, y, out);
}

// Round 13
// 24.174 us; speedup vs baseline: 1.2653x; 1.2653x over previous
//
#include <hip/hip_runtime.h>

#define N 256
#define LANES 64
#define NPAIRS 264       // pairs: front pad [0,64), real [64,192), tail pad [192,264)
#define PPAD   64

typedef float f32x2 __attribute__((ext_vector_type(2)));
typedef float f32x4 __attribute__((ext_vector_type(4)));

// DPP wave_shr:1 — lane i gets src[i-1]; lane 0 gets +INF.
__device__ __forceinline__ float dpp_shr1_inf(float v) {
    return __int_as_float(__builtin_amdgcn_update_dpp(
        0x7f800000, __float_as_int(v), 0x138 /*wave_shr:1*/, 0xf, 0xf, false));
}

// One wave per batch; lane t owns rows 4t..4t+3; 2 columns (1 pair) per step.
// LDS pair layout is component-interleaved so ds_read_b128 yields PACKED
// operands for v_pk_fma_f32 (CDNA full-rate packed fp32): the two columns'
// cost FMA trees fuse into one packed tree. Branchless pads, 2-deep
// double-buffered prefetch (R11 structure).
__global__ __launch_bounds__(64) void frechet_pk(
    const float* __restrict__ x,   // [B, 256, 3]
    const float* __restrict__ y,   // [B, 256, 3]
    float* __restrict__ out)       // [B]
{
    const int b = blockIdx.x;
    const int t = threadIdx.x;     // 0..63

    const float INF = __builtin_inff();

    // pair p at swizzled slot p^((p>>2)&3); pair = 2 f32x4:
    //   [0] = {y0(c0), y0(c1), y1(c0), y1(c1)}
    //   [1] = {y2(c0), y2(c1), ss(c0), ss(c1)}   ss = |y|^2
    __shared__ f32x4 ldsY[2 * NPAIRS];

    // pads: cost components 0, ss = +INF  -> cell value = +INF (DP boundary)
    {
        const f32x4 pad0 = {0.0f, 0.0f, 0.0f, 0.0f};
        const f32x4 pad1 = {0.0f, 0.0f, INF, INF};
        const int pf = t;
        const int sf = pf ^ ((pf >> 2) & 3);
        ldsY[2 * sf]     = pad0;
        ldsY[2 * sf + 1] = pad1;
        for (int pp = 192 + t; pp < NPAIRS; pp += 64) {
            const int st = pp ^ ((pp >> 2) & 3);
            ldsY[2 * st]     = pad0;
            ldsY[2 * st + 1] = pad1;
        }
    }

    // stage real y, 2 pairs per lane, component-interleaved
    #pragma unroll
    for (int k = 0; k < 2; ++k) {
        const int pr = t + 64 * k;           // real pair 0..127
        const int base = (b * N + 2 * pr) * 3;
        const float a0x = y[base + 0], a0y = y[base + 1], a0z = y[base + 2];
        const float a1x = y[base + 3], a1y = y[base + 4], a1z = y[base + 5];
        const float ss0 = a0x*a0x + a0y*a0y + a0z*a0z;
        const float ss1 = a1x*a1x + a1y*a1y + a1z*a1z;
        const int p = pr + PPAD;
        const int slot = p ^ ((p >> 2) & 3);
        const f32x4 w0 = {a0x, a1x, a0y, a1y};
        const f32x4 w1 = {a0z, a1z, ss0, ss1};
        ldsY[2 * slot]     = w0;
        ldsY[2 * slot + 1] = w1;
    }

    // x rows 4t..4t+3 -> packed broadcast constants: cost = |x|^2+|y|^2-2x.y
    f32x2 xp0[4], xp1[4], xp2[4], sxp[4];
    #pragma unroll
    for (int r = 0; r < 4; ++r) {
        const float a0 = x[(b * N + 4 * t + r) * 3 + 0];
        const float a1 = x[(b * N + 4 * t + r) * 3 + 1];
        const float a2 = x[(b * N + 4 * t + r) * 3 + 2];
        const float m0 = -2.0f * a0, m1 = -2.0f * a1, m2 = -2.0f * a2;
        const float s  = a0 * a0 + a1 * a1 + a2 * a2;
        xp0[r].x = m0; xp0[r].y = m0;
        xp1[r].x = m1; xp1[r].y = m1;
        xp2[r].x = m2; xp2[r].y = m2;
        sxp[r].x = s;  sxp[r].y = s;
    }
    __syncthreads();

    float lv0 = INF, lv1 = INF, lv2 = INF, lv3 = INF;
    float cb0 = INF, cb1 = INF;
    float diagv = (t == 0) ? 0.0f : INF;   // seeds D[0][0]

    // one DP step consuming interleaved pair (Q0, Q1)
    #define STEP(Q0, Q1)                                                          \
    {                                                                             \
        const float u0 = dpp_shr1_inf(cb0);                                       \
        const float u1 = dpp_shr1_inf(cb1);                                       \
        const f32x2 y0p = (Q0).xy, y1p = (Q0).zw;                                 \
        const f32x2 y2p = (Q1).xy, sab = (Q1).zw;                                 \
        const f32x2 c0p = __builtin_elementwise_fma(xp0[0], y0p,                  \
                          __builtin_elementwise_fma(xp1[0], y1p,                  \
                          __builtin_elementwise_fma(xp2[0], y2p, sxp[0] + sab))); \
        const f32x2 c1p = __builtin_elementwise_fma(xp0[1], y0p,                  \
                          __builtin_elementwise_fma(xp1[1], y1p,                  \
                          __builtin_elementwise_fma(xp2[1], y2p, sxp[1] + sab))); \
        const f32x2 c2p = __builtin_elementwise_fma(xp0[2], y0p,                  \
                          __builtin_elementwise_fma(xp1[2], y1p,                  \
                          __builtin_elementwise_fma(xp2[2], y2p, sxp[2] + sab))); \
        const f32x2 c3p = __builtin_elementwise_fma(xp0[3], y0p,                  \
                          __builtin_elementwise_fma(xp1[3], y1p,                  \
                          __builtin_elementwise_fma(xp2[3], y2p, sxp[3] + sab))); \
        const float v0 = fmaxf(c0p.x, fminf(fminf(u0, lv0), diagv));              \
        const float v1 = fmaxf(c1p.x, fminf(fminf(v0, lv1), lv0));                \
        const float v2 = fmaxf(c2p.x, fminf(fminf(v1, lv2), lv1));                \
        const float v3 = fmaxf(c3p.x, fminf(fminf(v2, lv3), lv2));                \
        const float w0 = fmaxf(c0p.y, fminf(fminf(u1, v0), u0));                  \
        const float w1 = fmaxf(c1p.y, fminf(fminf(w0, v1), v0));                  \
        const float w2 = fmaxf(c2p.y, fminf(fminf(w1, v2), v1));                  \
        const float w3 = fmaxf(c3p.y, fminf(fminf(w2, v3), v2));                  \
        lv0 = w0; lv1 = w1; lv2 = w2; lv3 = w3;                                   \
        cb0 = v3; cb1 = w3;                                                       \
        diagv = u1;                                                               \
    }

    // prologue: A <- pair(step 0), B <- pair(step 1)
    int pA = PPAD - t;         // in [1, 64]
    int pB = pA + 1;
    f32x4 yA0, yA1, yB0, yB1;
    {
        const int sA = pA ^ ((pA >> 2) & 3);
        yA0 = ldsY[2 * sA]; yA1 = ldsY[2 * sA + 1];
        const int sB = pB ^ ((pB >> 2) & 3);
        yB0 = ldsY[2 * sB]; yB1 = ldsY[2 * sB + 1];
    }
    pA += 2; pB += 2;

    // steps 0..189 as 95 double-iterations; epilogue = step 190
    #pragma unroll 1
    for (int k = 0; k < 95; ++k) {
        STEP(yA0, yA1);                       // even step: consume A
        {                                     // reload A for step +2
            const int sA = pA ^ ((pA >> 2) & 3);
            yA0 = ldsY[2 * sA]; yA1 = ldsY[2 * sA + 1];
            pA += 2;
        }
        STEP(yB0, yB1);                       // odd step: consume B
        {                                     // reload B for step +2
            const int sB = pB ^ ((pB >> 2) & 3);
            yB0 = ldsY[2 * sB]; yB1 = ldsY[2 * sB + 1];
            pB += 2;
        }
    }
    STEP(yA0, yA1);                           // step 190

    #undef STEP

    if (t == LANES - 1)
        out[b] = cb1;   // D[255][255]
}

extern "C" void kernel_launch(void* const* d_in, const int* in_sizes, int n_in,
                              void* d_out, int out_size, void* d_ws, size_t ws_size,
                              hipStream_t stream) {
    const float* x = (const float*)d_in[0];
    const float* y = (const float*)d_in[1];
    float* out = (float*)d_out;

    const int B = in_sizes[0] / (N * 3);   // 128
    frechet_pk<<<B, LANES, 0, stream>>>(x, y, out);
}

// Round 14
// 22.208 us; speedup vs baseline: 1.3773x; 1.0885x over previous
//
#include <hip/hip_runtime.h>

#define N 256
#define LANES 64
#define NPAIRS 264       // pairs: front pad [0,64), real [64,192), tail pad [192,264)
#define PPAD   64

typedef float f32x2 __attribute__((ext_vector_type(2)));
typedef float f32x4 __attribute__((ext_vector_type(4)));

// DPP wave_shr:1 — lane i gets src[i-1]; lane 0 gets +INF.
__device__ __forceinline__ float dpp_shr1_inf(float v) {
    return __int_as_float(__builtin_amdgcn_update_dpp(
        0x7f800000, __float_as_int(v), 0x138 /*wave_shr:1*/, 0xf, 0xf, false));
}

// One wave per batch; lane t owns rows 4t..4t+3; 2 columns (1 pair) per step.
// Component-interleaved LDS pairs feed v_pk_fma_f32 directly. TRIPLE-buffered
// prefetch: each ds_read lands 2 full steps (~180 cyc) before its consumption
// wait, exceeding the ~120-cyc LDS latency -> no lgkmcnt stalls.
__global__ __launch_bounds__(64) void frechet_pk3(
    const float* __restrict__ x,   // [B, 256, 3]
    const float* __restrict__ y,   // [B, 256, 3]
    float* __restrict__ out)       // [B]
{
    const int b = blockIdx.x;
    const int t = threadIdx.x;     // 0..63

    const float INF = __builtin_inff();

    // pair p at swizzled slot p^((p>>2)&3); pair = 2 f32x4:
    //   [0] = {y0(c0), y0(c1), y1(c0), y1(c1)}
    //   [1] = {y2(c0), y2(c1), ss(c0), ss(c1)}   ss = |y|^2
    __shared__ f32x4 ldsY[2 * NPAIRS];

    // pads: cost components 0, ss = +INF -> cell value = +INF (DP boundary)
    {
        const f32x4 pad0 = {0.0f, 0.0f, 0.0f, 0.0f};
        const f32x4 pad1 = {0.0f, 0.0f, INF, INF};
        const int pf = t;
        const int sf = pf ^ ((pf >> 2) & 3);
        ldsY[2 * sf]     = pad0;
        ldsY[2 * sf + 1] = pad1;
        for (int pp = 192 + t; pp < NPAIRS; pp += 64) {
            const int st = pp ^ ((pp >> 2) & 3);
            ldsY[2 * st]     = pad0;
            ldsY[2 * st + 1] = pad1;
        }
    }

    // stage real y, 2 pairs per lane, component-interleaved
    #pragma unroll
    for (int k = 0; k < 2; ++k) {
        const int pr = t + 64 * k;           // real pair 0..127
        const int base = (b * N + 2 * pr) * 3;
        const float a0x = y[base + 0], a0y = y[base + 1], a0z = y[base + 2];
        const float a1x = y[base + 3], a1y = y[base + 4], a1z = y[base + 5];
        const float ss0 = a0x*a0x + a0y*a0y + a0z*a0z;
        const float ss1 = a1x*a1x + a1y*a1y + a1z*a1z;
        const int p = pr + PPAD;
        const int slot = p ^ ((p >> 2) & 3);
        const f32x4 w0 = {a0x, a1x, a0y, a1y};
        const f32x4 w1 = {a0z, a1z, ss0, ss1};
        ldsY[2 * slot]     = w0;
        ldsY[2 * slot + 1] = w1;
    }

    // x rows 4t..4t+3 -> packed broadcast constants: cost = |x|^2+|y|^2-2x.y
    f32x2 xp0[4], xp1[4], xp2[4], sxp[4];
    #pragma unroll
    for (int r = 0; r < 4; ++r) {
        const float a0 = x[(b * N + 4 * t + r) * 3 + 0];
        const float a1 = x[(b * N + 4 * t + r) * 3 + 1];
        const float a2 = x[(b * N + 4 * t + r) * 3 + 2];
        const float m0 = -2.0f * a0, m1 = -2.0f * a1, m2 = -2.0f * a2;
        const float s  = a0 * a0 + a1 * a1 + a2 * a2;
        xp0[r].x = m0; xp0[r].y = m0;
        xp1[r].x = m1; xp1[r].y = m1;
        xp2[r].x = m2; xp2[r].y = m2;
        sxp[r].x = s;  sxp[r].y = s;
    }
    __syncthreads();

    float lv0 = INF, lv1 = INF, lv2 = INF, lv3 = INF;
    float cb0 = INF, cb1 = INF;
    float diagv = (t == 0) ? 0.0f : INF;   // seeds D[0][0]

    // one DP step consuming interleaved pair (Q0, Q1)
    #define STEP(Q0, Q1)                                                          \
    {                                                                             \
        const float u0 = dpp_shr1_inf(cb0);                                       \
        const float u1 = dpp_shr1_inf(cb1);                                       \
        const f32x2 y0p = (Q0).xy, y1p = (Q0).zw;                                 \
        const f32x2 y2p = (Q1).xy, sab = (Q1).zw;                                 \
        const f32x2 c0p = __builtin_elementwise_fma(xp0[0], y0p,                  \
                          __builtin_elementwise_fma(xp1[0], y1p,                  \
                          __builtin_elementwise_fma(xp2[0], y2p, sxp[0] + sab))); \
        const f32x2 c1p = __builtin_elementwise_fma(xp0[1], y0p,                  \
                          __builtin_elementwise_fma(xp1[1], y1p,                  \
                          __builtin_elementwise_fma(xp2[1], y2p, sxp[1] + sab))); \
        const f32x2 c2p = __builtin_elementwise_fma(xp0[2], y0p,                  \
                          __builtin_elementwise_fma(xp1[2], y1p,                  \
                          __builtin_elementwise_fma(xp2[2], y2p, sxp[2] + sab))); \
        const f32x2 c3p = __builtin_elementwise_fma(xp0[3], y0p,                  \
                          __builtin_elementwise_fma(xp1[3], y1p,                  \
                          __builtin_elementwise_fma(xp2[3], y2p, sxp[3] + sab))); \
        const float v0 = fmaxf(c0p.x, fminf(fminf(u0, lv0), diagv));              \
        const float v1 = fmaxf(c1p.x, fminf(fminf(v0, lv1), lv0));                \
        const float v2 = fmaxf(c2p.x, fminf(fminf(v1, lv2), lv1));                \
        const float v3 = fmaxf(c3p.x, fminf(fminf(v2, lv3), lv2));                \
        const float w0 = fmaxf(c0p.y, fminf(fminf(u1, v0), u0));                  \
        const float w1 = fmaxf(c1p.y, fminf(fminf(w0, v1), v0));                  \
        const float w2 = fmaxf(c2p.y, fminf(fminf(w1, v2), v1));                  \
        const float w3 = fmaxf(c3p.y, fminf(fminf(w2, v3), v2));                  \
        lv0 = w0; lv1 = w1; lv2 = w2; lv3 = w3;                                   \
        cb0 = v3; cb1 = w3;                                                       \
        diagv = u1;                                                               \
    }

    #define RELOAD(Y0, Y1, P)                                                     \
    {                                                                             \
        const int _sl = (P) ^ (((P) >> 2) & 3);                                   \
        Y0 = ldsY[2 * _sl]; Y1 = ldsY[2 * _sl + 1];                               \
        (P) += 3;                                                                 \
    }

    // prologue: A,B,C <- pairs for steps 0,1,2
    int pA = PPAD - t;         // in [1, 64]
    int pB = pA + 1;
    int pC = pA + 2;
    f32x4 yA0, yA1, yB0, yB1, yC0, yC1;
    {
        const int sA = pA ^ ((pA >> 2) & 3);
        yA0 = ldsY[2 * sA]; yA1 = ldsY[2 * sA + 1];
        const int sB = pB ^ ((pB >> 2) & 3);
        yB0 = ldsY[2 * sB]; yB1 = ldsY[2 * sB + 1];
        const int sC = pC ^ ((pC >> 2) & 3);
        yC0 = ldsY[2 * sC]; yC1 = ldsY[2 * sC + 1];
    }
    pA += 3; pB += 3; pC += 3;

    // steps 0..188 as 63 triple-iterations; epilogue = steps 189, 190
    #pragma unroll 1
    for (int k = 0; k < 63; ++k) {
        STEP(yA0, yA1); RELOAD(yA0, yA1, pA);   // consumed again 3 steps later
        STEP(yB0, yB1); RELOAD(yB0, yB1, pB);
        STEP(yC0, yC1); RELOAD(yC0, yC1, pC);
    }
    STEP(yA0, yA1);                             // step 189
    STEP(yB0, yB1);                             // step 190

    #undef RELOAD
    #undef STEP

    if (t == LANES - 1)
        out[b] = cb1;   // D[255][255]
}

extern "C" void kernel_launch(void* const* d_in, const int* in_sizes, int n_in,
                              void* d_out, int out_size, void* d_ws, size_t ws_size,
                              hipStream_t stream) {
    const float* x = (const float*)d_in[0];
    const float* y = (const float*)d_in[1];
    float* out = (float*)d_out;

    const int B = in_sizes[0] / (N * 3);   // 128
    frechet_pk3<<<B, LANES, 0, stream>>>(x, y, out);
}

// Round 15
// 21.384 us; speedup vs baseline: 1.4304x; 1.0385x over previous
//
#include <hip/hip_runtime.h>

#define N 256
#define LANES 64
#define NPAIRS 264       // pairs: front pad [0,64), real [64,192), tail pad [192,264)
#define PPAD   64

typedef float f32x2 __attribute__((ext_vector_type(2)));
typedef float f32x4 __attribute__((ext_vector_type(4)));

// DPP wave_shr:1 — lane i gets src[i-1]; lane 0 gets +INF.
__device__ __forceinline__ float dpp_shr1_inf(float v) {
    return __int_as_float(__builtin_amdgcn_update_dpp(
        0x7f800000, __float_as_int(v), 0x138 /*wave_shr:1*/, 0xf, 0xf, false));
}

// One wave per batch; lane t owns rows 4t..4t+3; 2 columns (1 pair) per step.
// Component-interleaved LDS pairs feed v_pk_fma_f32. Triple-buffered prefetch.
// LINEAR pair addressing (no swizzle — bank multiplicity identical, measured
// conflicts negligible): A/B/C reload via ds_read_b128 immediate offsets off
// ONE base register; base += 9 pairs per unrolled-x3 iteration.
__global__ __launch_bounds__(64) void frechet_lin(
    const float* __restrict__ x,   // [B, 256, 3]
    const float* __restrict__ y,   // [B, 256, 3]
    float* __restrict__ out)       // [B]
{
    const int b = blockIdx.x;
    const int t = threadIdx.x;     // 0..63

    const float INF = __builtin_inff();

    // pair p at ldsY[2p], ldsY[2p+1]:
    //   [0] = {y0(c0), y0(c1), y1(c0), y1(c1)}
    //   [1] = {y2(c0), y2(c1), ss(c0), ss(c1)}   ss = |y|^2
    __shared__ f32x4 ldsY[2 * NPAIRS];

    // pads: cost components 0, ss = +INF -> cell value = +INF (DP boundary)
    {
        const f32x4 pad0 = {0.0f, 0.0f, 0.0f, 0.0f};
        const f32x4 pad1 = {0.0f, 0.0f, INF, INF};
        ldsY[2 * t]     = pad0;
        ldsY[2 * t + 1] = pad1;
        for (int pp = 192 + t; pp < NPAIRS; pp += 64) {
            ldsY[2 * pp]     = pad0;
            ldsY[2 * pp + 1] = pad1;
        }
    }

    // stage real y, 2 pairs per lane, component-interleaved
    #pragma unroll
    for (int k = 0; k < 2; ++k) {
        const int pr = t + 64 * k;           // real pair 0..127
        const int base = (b * N + 2 * pr) * 3;
        const float a0x = y[base + 0], a0y = y[base + 1], a0z = y[base + 2];
        const float a1x = y[base + 3], a1y = y[base + 4], a1z = y[base + 5];
        const float ss0 = a0x*a0x + a0y*a0y + a0z*a0z;
        const float ss1 = a1x*a1x + a1y*a1y + a1z*a1z;
        const int p = pr + PPAD;
        const f32x4 w0 = {a0x, a1x, a0y, a1y};
        const f32x4 w1 = {a0z, a1z, ss0, ss1};
        ldsY[2 * p]     = w0;
        ldsY[2 * p + 1] = w1;
    }

    // x rows 4t..4t+3 -> packed broadcast constants: cost = |x|^2+|y|^2-2x.y
    f32x2 xp0[4], xp1[4], xp2[4], sxp[4];
    #pragma unroll
    for (int r = 0; r < 4; ++r) {
        const float a0 = x[(b * N + 4 * t + r) * 3 + 0];
        const float a1 = x[(b * N + 4 * t + r) * 3 + 1];
        const float a2 = x[(b * N + 4 * t + r) * 3 + 2];
        const float m0 = -2.0f * a0, m1 = -2.0f * a1, m2 = -2.0f * a2;
        const float s  = a0 * a0 + a1 * a1 + a2 * a2;
        xp0[r].x = m0; xp0[r].y = m0;
        xp1[r].x = m1; xp1[r].y = m1;
        xp2[r].x = m2; xp2[r].y = m2;
        sxp[r].x = s;  sxp[r].y = s;
    }
    __syncthreads();

    float lv0 = INF, lv1 = INF, lv2 = INF, lv3 = INF;
    float cb0 = INF, cb1 = INF;
    float diagv = (t == 0) ? 0.0f : INF;   // seeds D[0][0]

    // one DP step consuming interleaved pair (Q0, Q1)
    #define STEP(Q0, Q1)                                                          \
    {                                                                             \
        const float u0 = dpp_shr1_inf(cb0);                                       \
        const float u1 = dpp_shr1_inf(cb1);                                       \
        const f32x2 y0p = (Q0).xy, y1p = (Q0).zw;                                 \
        const f32x2 y2p = (Q1).xy, sab = (Q1).zw;                                 \
        const f32x2 c0p = __builtin_elementwise_fma(xp0[0], y0p,                  \
                          __builtin_elementwise_fma(xp1[0], y1p,                  \
                          __builtin_elementwise_fma(xp2[0], y2p, sxp[0] + sab))); \
        const f32x2 c1p = __builtin_elementwise_fma(xp0[1], y0p,                  \
                          __builtin_elementwise_fma(xp1[1], y1p,                  \
                          __builtin_elementwise_fma(xp2[1], y2p, sxp[1] + sab))); \
        const f32x2 c2p = __builtin_elementwise_fma(xp0[2], y0p,                  \
                          __builtin_elementwise_fma(xp1[2], y1p,                  \
                          __builtin_elementwise_fma(xp2[2], y2p, sxp[2] + sab))); \
        const f32x2 c3p = __builtin_elementwise_fma(xp0[3], y0p,                  \
                          __builtin_elementwise_fma(xp1[3], y1p,                  \
                          __builtin_elementwise_fma(xp2[3], y2p, sxp[3] + sab))); \
        const float v0 = fmaxf(c0p.x, fminf(fminf(u0, lv0), diagv));              \
        const float v1 = fmaxf(c1p.x, fminf(fminf(v0, lv1), lv0));                \
        const float v2 = fmaxf(c2p.x, fminf(fminf(v1, lv2), lv1));                \
        const float v3 = fmaxf(c3p.x, fminf(fminf(v2, lv3), lv2));                \
        const float w0 = fmaxf(c0p.y, fminf(fminf(u1, v0), u0));                  \
        const float w1 = fmaxf(c1p.y, fminf(fminf(w0, v1), v0));                  \
        const float w2 = fmaxf(c2p.y, fminf(fminf(w1, v2), v1));                  \
        const float w3 = fmaxf(c3p.y, fminf(fminf(w2, v3), v2));                  \
        lv0 = w0; lv1 = w1; lv2 = w2; lv3 = w3;                                   \
        cb0 = v3; cb1 = w3;                                                       \
        diagv = u1;                                                               \
    }

    // prologue: A,B,C <- pairs q0, q0+1, q0+2 (steps 0,1,2)
    const int q0 = PPAD - t;     // in [1, 64]
    const f32x4* bp = &ldsY[2 * q0];
    f32x4 yA0 = bp[0], yA1 = bp[1];
    f32x4 yB0 = bp[2], yB1 = bp[3];
    f32x4 yC0 = bp[4], yC1 = bp[5];
    bp += 6;                     // -> pair q0+3

    // steps 0..188 as 63 triple-iterations (x3 unrolled -> 9 steps, 1 ptr add);
    // epilogue = steps 189, 190
    #pragma unroll 3
    for (int k = 0; k < 63; ++k) {
        STEP(yA0, yA1); yA0 = bp[0]; yA1 = bp[1];   // consumed 3 steps later
        STEP(yB0, yB1); yB0 = bp[2]; yB1 = bp[3];
        STEP(yC0, yC1); yC0 = bp[4]; yC1 = bp[5];
        bp += 6;
    }
    STEP(yA0, yA1);                                 // step 189
    STEP(yB0, yB1);                                 // step 190

    #undef STEP

    if (t == LANES - 1)
        out[b] = cb1;   // D[255][255]
}

extern "C" void kernel_launch(void* const* d_in, const int* in_sizes, int n_in,
                              void* d_out, int out_size, void* d_ws, size_t ws_size,
                              hipStream_t stream) {
    const float* x = (const float*)d_in[0];
    const float* y = (const float*)d_in[1];
    float* out = (float*)d_out;

    const int B = in_sizes[0] / (N * 3);   // 128
    frechet_lin<<<B, LANES, 0, stream>>>(x, y, out);
}

// Round 16
// 17.474 us; speedup vs baseline: 1.7505x; 1.2238x over previous
//
#include <hip/hip_runtime.h>

#define N 256
#define LANES 64
#define FRONT 128        // front-pad pairs per region
#define NPAIRS 260       // FRONT + 128 real + 4 tail pad
#define NSTEP 128        // uniform step count (skew-2 absorbs the ramp)

typedef float f32x2 __attribute__((ext_vector_type(2)));
typedef float f32x4 __attribute__((ext_vector_type(4)));

// DPP wave_shr:1 — lane i gets src[i-1]; lane 0 gets +INF.
__device__ __forceinline__ float dpp_shr1_inf(float v) {
    return __int_as_float(__builtin_amdgcn_update_dpp(
        0x7f800000, __float_as_int(v), 0x138 /*wave_shr:1*/, 0xf, 0xf, false));
}

// Bidirectional Frechet DP. Wave 0: forward DP on triangle i+j<=254 (+253
// captures). Wave 1: reverse DP (same recurrence on reversed x,y) on the
// complementary triangle. Skew-2: lane t processes pair p at step 2t+p, so
// every lane finishes its triangle at step 127 -> 128 uniform steps (vs 191
// for the full sweep). Cross-lane "up" values are delayed 2 steps via g/h
// delay-register renaming (no movs). Cut combine (exact min/max algebra):
//  ans = min_r [ max(F254[r], min(R255[255-r], R255[254-r], R254[254-r])),
//                max(F253[r], R255[254-r]) ]
__global__ __launch_bounds__(128) void frechet_bidir(
    const float* __restrict__ x,   // [B, 256, 3]
    const float* __restrict__ y,   // [B, 256, 3]
    float* __restrict__ out)       // [B]
{
    const int b   = blockIdx.x;
    const int tid = threadIdx.x;
    const int wid = tid >> 6;      // 0 = forward, 1 = reverse
    const int t   = tid & 63;      // lane

    const float INF = __builtin_inff();

    // per-wave y regions (component-interleaved pairs) + cut-capture arrays
    __shared__ f32x4 ldsY[2][2 * NPAIRS];
    __shared__ float Fd253[256], Fd254[256], Rd254[256], Rd255[256];

    f32x4* reg = ldsY[wid];

    // pads: cost components 0, ss=+INF -> cell = +INF (DP boundary)
    {
        const f32x4 pad0 = {0.0f, 0.0f, 0.0f, 0.0f};
        const f32x4 pad1 = {0.0f, 0.0f, INF, INF};
        reg[2 * t]            = pad0;  reg[2 * t + 1]            = pad1;
        reg[2 * (t + 64)]     = pad0;  reg[2 * (t + 64) + 1]     = pad1;
        if (t < 4) {
            const int pp = FRONT + 128 + t;
            reg[2 * pp] = pad0;  reg[2 * pp + 1] = pad1;
        }
    }

    // stage oriented y: wave 0 cols c, wave 1 cols 255-c
    #pragma unroll
    for (int k = 0; k < 2; ++k) {
        const int pr = t + 64 * k;           // real pair 0..127
        const int c0 = 2 * pr, c1 = 2 * pr + 1;
        const int oc0 = wid ? (255 - c0) : c0;
        const int oc1 = wid ? (255 - c1) : c1;
        const float a0x = y[(b * N + oc0) * 3 + 0];
        const float a0y = y[(b * N + oc0) * 3 + 1];
        const float a0z = y[(b * N + oc0) * 3 + 2];
        const float a1x = y[(b * N + oc1) * 3 + 0];
        const float a1y = y[(b * N + oc1) * 3 + 1];
        const float a1z = y[(b * N + oc1) * 3 + 2];
        const float ss0 = a0x*a0x + a0y*a0y + a0z*a0z;
        const float ss1 = a1x*a1x + a1y*a1y + a1z*a1z;
        const int p = FRONT + pr;
        const f32x4 w0 = {a0x, a1x, a0y, a1y};
        const f32x4 w1 = {a0z, a1z, ss0, ss1};
        reg[2 * p]     = w0;
        reg[2 * p + 1] = w1;
    }

    // oriented x rows 4t..4t+3 -> packed constants: cost = |x|^2+|y|^2-2x.y
    f32x2 xp0[4], xp1[4], xp2[4], sxp[4];
    #pragma unroll
    for (int r = 0; r < 4; ++r) {
        const int orow = wid ? (255 - (4 * t + r)) : (4 * t + r);
        const float a0 = x[(b * N + orow) * 3 + 0];
        const float a1 = x[(b * N + orow) * 3 + 1];
        const float a2 = x[(b * N + orow) * 3 + 2];
        const float m0 = -2.0f * a0, m1 = -2.0f * a1, m2 = -2.0f * a2;
        const float s  = a0 * a0 + a1 * a1 + a2 * a2;
        xp0[r].x = m0; xp0[r].y = m0;
        xp1[r].x = m1; xp1[r].y = m1;
        xp2[r].x = m2; xp2[r].y = m2;
        sxp[r].x = s;  sxp[r].y = s;
    }
    __syncthreads();

    float lv0 = INF, lv1 = INF, lv2 = INF, lv3 = INF;
    float g0 = INF, g1 = INF;              // cb delayed 2 steps (even parity)
    float h0 = INF, h1 = INF;              // cb delayed 2 steps (odd parity)
    float diagv = (t == 0) ? 0.0f : INF;   // seeds D[0][0]
    float V0, V1, V2, V3, W0, W1, W2, W3;  // persistent step outputs

    // one DP step; Q0v/Q1v = delay regs (read 2-step-old cb, then hold new cb)
    #define STEP(Q0v, Q1v, Y0, Y1)                                            \
    {                                                                         \
        const float u0 = dpp_shr1_inf(Q0v);                                   \
        const float u1 = dpp_shr1_inf(Q1v);                                   \
        const f32x2 y0p = (Y0).xy, y1p = (Y0).zw;                             \
        const f32x2 y2p = (Y1).xy, sab = (Y1).zw;                             \
        const f32x2 c0p = __builtin_elementwise_fma(xp0[0], y0p,              \
                          __builtin_elementwise_fma(xp1[0], y1p,              \
                          __builtin_elementwise_fma(xp2[0], y2p, sxp[0] + sab))); \
        const f32x2 c1p = __builtin_elementwise_fma(xp0[1], y0p,              \
                          __builtin_elementwise_fma(xp1[1], y1p,              \
                          __builtin_elementwise_fma(xp2[1], y2p, sxp[1] + sab))); \
        const f32x2 c2p = __builtin_elementwise_fma(xp0[2], y0p,              \
                          __builtin_elementwise_fma(xp1[2], y1p,              \
                          __builtin_elementwise_fma(xp2[2], y2p, sxp[2] + sab))); \
        const f32x2 c3p = __builtin_elementwise_fma(xp0[3], y0p,              \
                          __builtin_elementwise_fma(xp1[3], y1p,              \
                          __builtin_elementwise_fma(xp2[3], y2p, sxp[3] + sab))); \
        V0 = fmaxf(c0p.x, fminf(fminf(u0, lv0), diagv));                      \
        V1 = fmaxf(c1p.x, fminf(fminf(V0, lv1), lv0));                        \
        V2 = fmaxf(c2p.x, fminf(fminf(V1, lv2), lv1));                        \
        V3 = fmaxf(c3p.x, fminf(fminf(V2, lv3), lv2));                        \
        W0 = fmaxf(c0p.y, fminf(fminf(u1, V0), u0));                          \
        W1 = fmaxf(c1p.y, fminf(fminf(W0, V1), V0));                          \
        W2 = fmaxf(c2p.y, fminf(fminf(W1, V2), V1));                          \
        W3 = fmaxf(c3p.y, fminf(fminf(W2, V3), V2));                          \
        lv0 = W0; lv1 = W1; lv2 = W2; lv3 = W3;                               \
        Q0v = V3; Q1v = W3;                                                   \
        diagv = u1;                                                           \
    }

    // prologue: A,B,C <- LDS pairs q0, q0+1, q0+2 (steps 0,1,2)
    const int q0 = FRONT - 2 * t;          // in [2, 128]
    const f32x4* bp = &reg[2 * q0];
    f32x4 yA0 = bp[0], yA1 = bp[1];
    f32x4 yB0 = bp[2], yB1 = bp[3];
    f32x4 yC0 = bp[4], yC1 = bp[5];
    bp += 6;

    // steps 0..119: 20 iterations x 6 steps (g/h parity period = 2, buffers 3)
    #pragma unroll 1
    for (int k = 0; k < 20; ++k) {
        STEP(g0, g1, yA0, yA1); yA0 = bp[0];  yA1 = bp[1];
        STEP(h0, h1, yB0, yB1); yB0 = bp[2];  yB1 = bp[3];
        STEP(g0, g1, yC0, yC1); yC0 = bp[4];  yC1 = bp[5];
        STEP(h0, h1, yA0, yA1); yA0 = bp[6];  yA1 = bp[7];
        STEP(g0, g1, yB0, yB1); yB0 = bp[8];  yB1 = bp[9];
        STEP(h0, h1, yC0, yC1); yC0 = bp[10]; yC1 = bp[11];
        bp += 12;
    }
    // steps 120..124 with reloads
    STEP(g0, g1, yA0, yA1); yA0 = bp[0]; yA1 = bp[1];   // s=120
    STEP(h0, h1, yB0, yB1); yB0 = bp[2]; yB1 = bp[3];   // s=121
    STEP(g0, g1, yC0, yC1); yC0 = bp[4]; yC1 = bp[5];   // s=122
    STEP(h0, h1, yA0, yA1); yA0 = bp[6]; yA1 = bp[7];   // s=123
    STEP(g0, g1, yB0, yB1); yB0 = bp[8]; yB1 = bp[9];   // s=124
    // peeled capture steps (pair 125-2t, 126-2t, 127-2t; invalid -> INF)
    STEP(h0, h1, yC0, yC1);                              // s=125
    if (wid == 0) { Fd253[4*t+2] = W2; Fd253[4*t+3] = V3; Fd254[4*t+3] = W3; }
    else          { Rd254[4*t+3] = W3; }
    STEP(g0, g1, yA0, yA1);                              // s=126
    if (wid == 0) { Fd253[4*t]   = W0; Fd253[4*t+1] = V1;
                    Fd254[4*t+1] = W1; Fd254[4*t+2] = V2; }
    else          { Rd255[4*t+2] = W2; Rd255[4*t+3] = V3;
                    Rd254[4*t+1] = W1; Rd254[4*t+2] = V2; }
    STEP(h0, h1, yB0, yB1);                              // s=127
    if (wid == 0) { Fd254[4*t]   = V0; }
    else          { Rd255[4*t]   = W0; Rd255[4*t+1] = V1; Rd254[4*t] = V0; }

    #undef STEP

    __syncthreads();

    // combine (wave 0): min over cut edges; invalid entries are INF
    if (wid == 0) {
        float m = INF;
        #pragma unroll
        for (int k = 0; k < 4; ++k) {
            const int r  = 4 * t + k;
            const int i2 = (254 - r) < 0 ? 0 : (254 - r);   // clamp (r=255 terms are INF)
            const float rn = Rd255[i2];
            const float ta = fmaxf(Fd254[r],
                                   fminf(fminf(Rd255[255 - r], rn), Rd254[i2]));
            const float tb = fmaxf(Fd253[r], rn);
            m = fminf(m, fminf(ta, tb));
        }
        #pragma unroll
        for (int off = 32; off >= 1; off >>= 1)
            m = fminf(m, __shfl_xor(m, off));
        if (t == 0) out[b] = m;
    }
}

extern "C" void kernel_launch(void* const* d_in, const int* in_sizes, int n_in,
                              void* d_out, int out_size, void* d_ws, size_t ws_size,
                              hipStream_t stream) {
    const float* x = (const float*)d_in[0];
    const float* y = (const float*)d_in[1];
    float* out = (float*)d_out;

    const int B = in_sizes[0] / (N * 3);   // 128
    frechet_bidir<<<B, 128, 0, stream>>>(x, y, out);
}